// Round 3
// baseline (31.993 us; speedup 1.0000x reference)
//
#include <hip/hip_runtime.h>

// WordPooler, two-phase, scatter-built index.
// Offsets are sorted ascending per row (PAD=-100 only in the tail), so each
// word value is one run -> scatter-mean == "copy first subword row or zeros".
//
// K0: hipMemsetAsync src to -1.
// K1 (scatter): thread (b,s) marks run-starts: src[b*T + v] = s. No dependent
//     load chain (the round-2 binary search was 12 serial L2 loads).
// K2 (gather): one wave per word; 1 broadcast src load, 4 independent
//     nontemporal float4 loads + stores per lane (D=1024).

typedef float v4f __attribute__((ext_vector_type(4)));

__global__ void __launch_bounds__(256)
wp_scatter_kernel(const int* __restrict__ ofs, int* __restrict__ src,
                  int S, int T) {
    const int s = blockIdx.x * 256 + threadIdx.x;
    const int b = blockIdx.y;
    if (s >= S) return;
    const int* __restrict__ row = ofs + (size_t)b * S;
    const int v = row[s];
    if (v < 0) return;                          // PAD tail
    const int prev = (s == 0) ? -1 : row[s - 1];
    if (v != prev) src[(size_t)b * T + v] = s;  // unique first-token-of-word
}

__global__ void __launch_bounds__(256)
wp_gather_kernel(const float* __restrict__ hs, const int* __restrict__ src,
                 float* __restrict__ out, int S, int T, int D) {
    const int wave = threadIdx.x >> 6;            // 4 waves/block
    const int lane = threadIdx.x & 63;
    const int t = blockIdx.x * 4 + wave;          // word id within batch b
    const int b = blockIdx.y;
    const size_t word = (size_t)b * T + t;
    const int s = src[word];                      // wave-uniform broadcast
    v4f* __restrict__ o = (v4f*)(out + word * (size_t)D);
    if (s >= 0) {
        const v4f* __restrict__ in =
            (const v4f*)(hs + ((size_t)b * S + s) * (size_t)D);
        v4f r0 = __builtin_nontemporal_load(in + lane);
        v4f r1 = __builtin_nontemporal_load(in + lane + 64);
        v4f r2 = __builtin_nontemporal_load(in + lane + 128);
        v4f r3 = __builtin_nontemporal_load(in + lane + 192);
        __builtin_nontemporal_store(r0, o + lane);
        __builtin_nontemporal_store(r1, o + lane + 64);
        __builtin_nontemporal_store(r2, o + lane + 128);
        __builtin_nontemporal_store(r3, o + lane + 192);
    } else {
        v4f z = (v4f)(0.f);
        __builtin_nontemporal_store(z, o + lane);
        __builtin_nontemporal_store(z, o + lane + 64);
        __builtin_nontemporal_store(z, o + lane + 128);
        __builtin_nontemporal_store(z, o + lane + 192);
    }
}

extern "C" void kernel_launch(void* const* d_in, const int* in_sizes, int n_in,
                              void* d_out, int out_size, void* d_ws, size_t ws_size,
                              hipStream_t stream) {
    const float* hs  = (const float*)d_in[0];   // (B,S,D) f32
    const int*   ofs = (const int*)d_in[1];     // (B,S) int32
    float* out = (float*)d_out;                 // (B,T,D) f32
    int* src = (int*)d_ws;                      // (B,T) scratch

    const int B = 8;
    const int BS = in_sizes[1];
    const int S = BS / B;
    const int D = in_sizes[0] / BS;
    const int T = out_size / (B * D);

    hipMemsetAsync(src, 0xFF, (size_t)B * T * sizeof(int), stream);  // src = -1

    dim3 g1((S + 255) / 256, B);
    wp_scatter_kernel<<<g1, 256, 0, stream>>>(ofs, src, S, T);

    dim3 g2(T / 4, B);
    wp_gather_kernel<<<g2, 256, 0, stream>>>(hs, src, out, S, T, D);
}

// Round 4
// 28.626 us; speedup vs baseline: 1.1176x; 1.1176x over previous
//
#include <hip/hip_runtime.h>

// WordPooler, two-phase, scatter-built self-verifying index.
// Offsets sorted ascending per row (PAD=-100 only in the tail) -> each word is
// one run -> reference's scatter-mean == "copy first subword row, else zeros".
//
// K1 (scatter): thread (b,s) marks run-starts: src[b*T + v] = s. Fully
//     parallel, no dependent-load chain.
// K2 (gather): one wave per word. Reads src[b,t]=s and VERIFIES it
//     (ofs[b,s]==t && ofs[b,s-1]!=t) before use, so absent words -- whose src
//     slot K1 never wrote -- yield zeros no matter what garbage d_ws holds.
//     No memset node needed; 2 dispatches total. Cached (non-NT) loads/stores
//     so the ~118 MiB per-replay working set can live in the 256 MiB L3.

typedef float v4f __attribute__((ext_vector_type(4)));

__global__ void __launch_bounds__(256)
wp_scatter_kernel(const int* __restrict__ ofs, int* __restrict__ src,
                  int S, int T) {
    const int s = blockIdx.x * 256 + threadIdx.x;
    const int b = blockIdx.y;
    if (s >= S) return;
    const int* __restrict__ row = ofs + (size_t)b * S;
    const int v = row[s];
    if (v < 0) return;                          // PAD tail
    const int prev = (s == 0) ? -1 : row[s - 1];
    if (v != prev) src[(size_t)b * T + v] = s;  // unique first-token-of-word
}

__global__ void __launch_bounds__(256)
wp_gather_kernel(const float* __restrict__ hs, const int* __restrict__ ofs,
                 const int* __restrict__ src, float* __restrict__ out,
                 int S, int T, int D) {
    const int wave = threadIdx.x >> 6;            // 4 waves/block
    const int lane = threadIdx.x & 63;
    const int t = blockIdx.x * 4 + wave;          // word id within batch b
    const int b = blockIdx.y;
    const size_t word = (size_t)b * T + t;
    const int s = src[word];                      // wave-uniform

    // Verify: s must be the first token of word t (makes garbage src safe).
    bool present = false;
    if ((unsigned)s < (unsigned)S) {
        const int* __restrict__ row = ofs + (size_t)b * S;
        const int v = row[s];
        const int prev = (s == 0) ? -1 : row[s - 1];
        present = (v == t) & (prev != t);
    }

    v4f* __restrict__ o = (v4f*)(out + word * (size_t)D);
    if (present) {
        const v4f* __restrict__ in =
            (const v4f*)(hs + ((size_t)b * S + s) * (size_t)D);
        v4f r0 = in[lane];
        v4f r1 = in[lane + 64];
        v4f r2 = in[lane + 128];
        v4f r3 = in[lane + 192];
        o[lane]       = r0;
        o[lane + 64]  = r1;
        o[lane + 128] = r2;
        o[lane + 192] = r3;
    } else {
        const v4f z = (v4f)(0.f);
        o[lane]       = z;
        o[lane + 64]  = z;
        o[lane + 128] = z;
        o[lane + 192] = z;
    }
}

extern "C" void kernel_launch(void* const* d_in, const int* in_sizes, int n_in,
                              void* d_out, int out_size, void* d_ws, size_t ws_size,
                              hipStream_t stream) {
    const float* hs  = (const float*)d_in[0];   // (B,S,D) f32
    const int*   ofs = (const int*)d_in[1];     // (B,S) int32
    float* out = (float*)d_out;                 // (B,T,D) f32
    int* src = (int*)d_ws;                      // (B,T) scratch (no init needed)

    const int B = 8;
    const int BS = in_sizes[1];
    const int S = BS / B;
    const int D = in_sizes[0] / BS;
    const int T = out_size / (B * D);

    dim3 g1((S + 255) / 256, B);
    wp_scatter_kernel<<<g1, 256, 0, stream>>>(ofs, src, S, T);

    dim3 g2(T / 4, B);
    wp_gather_kernel<<<g2, 256, 0, stream>>>(hs, ofs, src, out, S, T, D);
}